// Round 6
// baseline (96.068 us; speedup 1.0000x reference)
//
#include <hip/hip_runtime.h>

#define BB 4
#define CC 32
#define HH 512
#define WW 512
#define TS 16          // 16x16 output tile per 256-thread block
#define SH 24          // staged rows: tile_origin-4 .. +19 (y0 in [-4,+18], y1=y0+1)
#define SW 32          // staged cols: tile_origin-4 .. +27
#define CB 4           // channels per batch
#define NB (CC / CB)   // 8 batches
#define CSTRIDE (SH * SW)     // 768 floats / channel  (= 3 x 1KB wave loads)
#define BUFSZ (CB * CSTRIDE)  // 3072 floats / buffer

typedef float f2v __attribute__((ext_vector_type(2), aligned(4)));
typedef const __attribute__((address_space(1))) float gfloat;
typedef __attribute__((address_space(3))) float lfloat;

__device__ __forceinline__ void stage16(const float* g, float* l) {
    // async global->LDS, 16B/lane; LDS dest = l + lane*16 (linear, wave-uniform base)
    __builtin_amdgcn_global_load_lds((gfloat*)g, (lfloat*)l, 16, 0, 0);
}

__global__ __launch_bounds__(256) void warp_bilinear_kernel(
    const float* __restrict__ src,
    const float* __restrict__ flow,
    float* __restrict__ out)
{
    const int HW = HH * WW;
    __shared__ float smem[2 * BUFSZ];   // 24 KB -> 6 blocks/CU

    // Bijective XCD swizzle (gridDim.x == 4096, divisible by 8).
    int nper = gridDim.x >> 3;
    int bid = (blockIdx.x & 7) * nper + (blockIdx.x >> 3);

    int b  = bid >> 10;
    int ty = (bid >> 5) & 31;
    int tx = bid & 31;

    int tid  = threadIdx.x;
    int lane = tid & 63;
    int wv   = tid >> 6;        // wave id 0..3 (stages channel cb*4+wv)
    int lx   = tid & 15;
    int ly   = tid >> 4;

    int h = ty * TS + ly;
    int w = tx * TS + lx;
    int p = h * WW + w;

    int row_base = ty * TS - 4;
    int col_base = tx * TS - 4;

    const float* sb = src + (size_t)b * CC * HW;
    float*       ob = out + (size_t)b * CC * HW;

    float fy = __builtin_nontemporal_load(flow + (b * 2 + 0) * HW + p);
    float fx = __builtin_nontemporal_load(flow + (b * 2 + 1) * HW + p);

    float yy = fminf(fmaxf((float)h + fy, 0.0f), (float)(HH - 1));
    float xx = fminf(fmaxf((float)w + fx, 0.0f), (float)(WW - 1));

    // Border fold (== reference exactly): x1 = x0+1 always, weight 0 at border.
    int y0 = min((int)floorf(yy), HH - 2);
    int x0 = min((int)floorf(xx), WW - 2);
    float wy = yy - (float)y0;
    float wx = xx - (float)x0;

    float w00 = (1.0f - wy) * (1.0f - wx);
    float w01 = (1.0f - wy) * wx;
    float w10 = wy * (1.0f - wx);
    float w11 = wy * wx;

    int r0 = y0 - row_base;
    int c0 = x0 - col_base;
    bool in_tile = ((unsigned)r0 <= (SH - 2)) && ((unsigned)c0 <= (SW - 2));

    // LDS layout: slot (r, j) holds element (r, j ^ ((r&7)<<2)) -> read slot
    // j = c ^ swz(r). Bank = j mod 32 now depends on row -> no multi-row
    // same-bank pileup.
    int sw0 = (r0 & 7) << 2;
    int sw1 = ((r0 + 1) & 7) << 2;
    int o00 = r0 * SW + (c0 ^ sw0);
    int o01 = r0 * SW + ((c0 + 1) ^ sw0);
    int o10 = (r0 + 1) * SW + (c0 ^ sw1);
    int o11 = (r0 + 1) * SW + ((c0 + 1) ^ sw1);

    int i0 = y0 * WW + x0;     // global fallback (rare: |flow| beyond halo)
    int i1 = i0 + WW;

    bool interior_x = (tx >= 1) && (tx <= 30);   // block-uniform

    // Per-lane staging constants: slot s = it*256 + lane*4 covers
    // (r = it*8 + lane>>3, j = (lane&7)*4 .. +3); source col = col_base + j^swz.
    int rlane = lane >> 3;
    int cofs  = ((lane & 7) << 2) ^ (rlane << 2);
    int scol  = col_base + cofs;

    auto stage = [&](int cb_, int bi_) {
        const float* s_ = sb + (size_t)(cb_ * CB + wv) * HW;
        float* lb_ = &smem[bi_ * BUFSZ + wv * CSTRIDE];
        if (interior_x) {
            #pragma unroll
            for (int it = 0; it < 3; ++it) {
                int srow = min(max(row_base + it * 8 + rlane, 0), HH - 1);
                stage16(s_ + srow * WW + scol, lb_ + it * 256);
            }
        } else {
            // edge-x: per-element clamp, same swizzled layout, reg->ds_write
            for (int e = lane; e < CSTRIDE; e += 64) {
                int r = e >> 5, j = e & 31;
                int c = j ^ ((r & 7) << 2);
                int srow = min(max(row_base + r, 0), HH - 1);
                int sc   = min(max(col_base + c, 0), WW - 1);
                lb_[e] = s_[srow * WW + sc];
            }
        }
    };

    stage(0, 0);   // prologue

    #pragma unroll
    for (int cb = 0; cb < NB; ++cb) {
        if (cb + 1 < NB) stage(cb + 1, (cb + 1) & 1);
        // Counted wait: newest 3 loads (next batch's stage) stay in flight;
        // everything older (this batch's stage) is guaranteed complete
        // (loads retire in issue order). Last iter drains fully.
        if (cb + 1 < NB) asm volatile("s_waitcnt vmcnt(3)" ::: "memory");
        else             asm volatile("s_waitcnt vmcnt(0)" ::: "memory");
        asm volatile("s_waitcnt lgkmcnt(0)" ::: "memory");  // edge-path ds_writes
        __builtin_amdgcn_s_barrier();

        const float* lb = &smem[(cb & 1) * BUFSZ];
        if (in_tile) {
            #pragma unroll
            for (int k = 0; k < CB; ++k) {
                const float* l = lb + k * CSTRIDE;
                float v = l[o00] * w00 + l[o01] * w01
                        + l[o10] * w10 + l[o11] * w11;
                __builtin_nontemporal_store(v, ob + (cb * CB + k) * HW + p);
            }
        } else {
            #pragma unroll
            for (int k = 0; k < CB; ++k) {
                const float* s = sb + (cb * CB + k) * HW;
                f2v t  = *(const f2v*)(s + i0);
                f2v bt = *(const f2v*)(s + i1);
                float v = t.x * w00 + t.y * w01 + bt.x * w10 + bt.y * w11;
                __builtin_nontemporal_store(v, ob + (cb * CB + k) * HW + p);
            }
        }
        if (cb + 1 < NB) __builtin_amdgcn_s_barrier();  // protect buf before overwrite
    }
}

extern "C" void kernel_launch(void* const* d_in, const int* in_sizes, int n_in,
                              void* d_out, int out_size, void* d_ws, size_t ws_size,
                              hipStream_t stream) {
    const float* src  = (const float*)d_in[0];
    const float* flow = (const float*)d_in[1];
    float* out = (float*)d_out;

    const int nblocks = BB * (HH / TS) * (WW / TS);   // 4096, divisible by 8
    warp_bilinear_kernel<<<nblocks, 256, 0, stream>>>(src, flow, out);
}